// Round 9
// baseline (54.919 us; speedup 1.0000x reference)
//
#include <hip/hip_runtime.h>

typedef short s16x8 __attribute__((ext_vector_type(8)));
typedef float f32x4 __attribute__((ext_vector_type(4)));
typedef unsigned short u16;

#define BATCH 512
#define HD    1023
#define K0    2048
#define N0    2048
#define N1    1024
#define N2    512

// round-to-nearest-even f32 -> bf16 (scalar path)
__device__ __forceinline__ u16 f2bf(float f) {
  unsigned u = __builtin_bit_cast(unsigned, f);
  unsigned r = (u + 0x7fffu + ((u >> 16) & 1u)) >> 16;
  return (u16)r;
}

// packed RNE convert: 8 f32 -> 8 bf16 in 4 VALU ops
__device__ __forceinline__ s16x8 pack8(f32x4 a, f32x4 b) {
  union { unsigned u[4]; s16x8 v; } r;
  asm("v_cvt_pk_bf16_f32 %0, %1, %2" : "=v"(r.u[0]) : "v"(a[0]), "v"(a[1]));
  asm("v_cvt_pk_bf16_f32 %0, %1, %2" : "=v"(r.u[1]) : "v"(a[2]), "v"(a[3]));
  asm("v_cvt_pk_bf16_f32 %0, %1, %2" : "=v"(r.u[2]) : "v"(b[0]), "v"(b[1]));
  asm("v_cvt_pk_bf16_f32 %0, %1, %2" : "=v"(r.u[3]) : "v"(b[2]), "v"(b[3]));
  return r.v;
}

// 16B load from 4B-aligned source (h_drug rows have odd length 1023)
__device__ __forceinline__ f32x4 ld4u(const float* p) {
  f32x4 v; __builtin_memcpy(&v, p, 16); return v;
}

// ================= K1: fused gather + gemm1 ==========================
// y1 = relu( X[512 x 2048] * W0[2048 x 2048]^T + b0 ) -> bf16,
// where X rows are gathered on the fly from h_drug/attrs via pairs.
// Tile 64 x 32, full K, 4 waves 2x2, grid 512 (2 blocks/CU), 4-deep
// register prefetch, T2 LDS swizzle, raw s_barrier + lgkmcnt(0) (T4), T5.

// load 8 consecutive x-elements for sample s, global elem e = t*64 + ac.
// bh0/bh1 = h_drug rows of the two drugs; att0/att1 = the attr scalars.
#define LDA(dx, dy, bh0, bh1, att0, att1, t) { \
  const float* bp = ((t) < 16) ? (bh0) : (bh1); \
  const int off = (((t) & 15) << 6) + ac; \
  dx = ld4u(bp + off); \
  if ((((t) & 15) == 15) && (ac == 56)) { \
    dy[0] = bp[off + 4]; dy[1] = bp[off + 5]; dy[2] = bp[off + 6]; \
    dy[3] = ((t) < 16) ? (att0) : (att1); \
  } else { \
    dy = ld4u(bp + off + 4); \
  } }

#define GIA(s, t) { \
  LDA(pax0_##s, pay0_##s, a0h0, a0h1, at00, at01, t) \
  LDA(pax1_##s, pay1_##s, a1h0, a1h1, at10, at11, t) \
  pw0_##s = *(const f32x4*)(wgp + (t) * 64); \
  pw1_##s = *(const f32x4*)(wgp + (t) * 64 + 4); }

#define GSA(s, t, DOLOAD) { \
  char* buf = lds[(s) & 1]; \
  *(s16x8*)(buf + awo0) = pack8(pax0_##s, pay0_##s); \
  *(s16x8*)(buf + awo1) = pack8(pax1_##s, pay1_##s); \
  *(s16x8*)(buf + 8192 + bwo0) = pack8(pw0_##s, pw1_##s); \
  asm volatile("s_waitcnt lgkmcnt(0)" ::: "memory"); \
  __builtin_amdgcn_s_barrier(); \
  asm volatile("" ::: "memory"); \
  if (DOLOAD) GIA(s, (t) + 4) \
  __builtin_amdgcn_s_setprio(1); \
  _Pragma("unroll") \
  for (int ks = 0; ks < 2; ++ks) { \
    const int kq = ((ks << 6) | lk) ^ sw; \
    s16x8 a0 = *(const s16x8*)(buf + aoff + kq); \
    s16x8 a1 = *(const s16x8*)(buf + aoff + 2048 + kq); \
    s16x8 b0 = *(const s16x8*)(buf + 8192 + boff + kq); \
    acc0 = __builtin_amdgcn_mfma_f32_16x16x32_bf16(a0, b0, acc0, 0, 0, 0); \
    acc1 = __builtin_amdgcn_mfma_f32_16x16x32_bf16(a1, b0, acc1, 0, 0, 0); \
  } \
  __builtin_amdgcn_s_setprio(0); }

__global__ __launch_bounds__(256) void k_fgemm1(
    const int* __restrict__ pairs, const float* __restrict__ attrs,
    const float* __restrict__ h_drug, const float* __restrict__ W,
    const float* __restrict__ bias, u16* __restrict__ Y) {
  constexpr int K = 2048, N = 2048;
  __shared__ char lds[2][8192 + 4096];  // A 8KB bf16 + B 4KB bf16
  const int tid = threadIdx.x;
  const int w = tid >> 6, l = tid & 63;
  const int wr = w >> 1, wc = w & 1;
  const int lrow = l & 15;
  const int lk = (l >> 4) << 4;
  const int sw = (lrow & 7) << 4;

  // XCD swizzle: each XCD owns 64 contiguous wgids (8 bn x 8 bm)
  const int wgid = (blockIdx.x & 7) * 64 + (blockIdx.x >> 3);
  const int bn = wgid >> 3, bm = wgid & 7;

  // ---- A gather setup: rows arow, arow+32 of this bm-panel ----
  const int arow = tid >> 3;          // 0..31
  const int ac = (tid & 7) * 8;       // elem col within BK=64
  const int s0 = bm * 64 + arow, s1 = s0 + 32;
  const float* a0h0 = h_drug + (size_t)pairs[2 * s0] * HD;
  const float* a0h1 = h_drug + (size_t)pairs[2 * s0 + 1] * HD;
  const float* a1h0 = h_drug + (size_t)pairs[2 * s1] * HD;
  const float* a1h1 = h_drug + (size_t)pairs[2 * s1 + 1] * HD;
  const float at00 = attrs[4 * s0 + 1], at01 = attrs[4 * s0 + 3];
  const float at10 = attrs[4 * s1 + 1], at11 = attrs[4 * s1 + 3];
  const int awo0 = (arow << 7) + ((ac * 2) ^ ((arow & 7) << 4));
  const int awo1 = awo0 + (32 << 7);  // (arow+32)&7 == arow&7

  // ---- W staging: row br (0..31), 8 floats at bq*8 ----
  const int br = tid >> 3, bq = tid & 7;
  const float* wgp = W + (size_t)(bn * 32 + br) * K + bq * 8;
  const int bwo0 = (br << 7) + ((bq * 16) ^ ((br & 7) << 4));

  const int aoff = (wr * 32 + lrow) * 128;
  const int boff = (wc * 16 + lrow) * 128;

  f32x4 acc0 = {}, acc1 = {};
  f32x4 pax0_0, pay0_0, pax1_0, pay1_0, pw0_0, pw1_0;
  f32x4 pax0_1, pay0_1, pax1_1, pay1_1, pw0_1, pw1_1;
  f32x4 pax0_2, pay0_2, pax1_2, pay1_2, pw0_2, pw1_2;
  f32x4 pax0_3, pay0_3, pax1_3, pay1_3, pw0_3, pw1_3;

  GIA(0, 0) GIA(1, 1) GIA(2, 2) GIA(3, 3)
  constexpr int NT = 32;
  int t = 0;
  for (; t < NT - 4; t += 4) {
    GSA(0, t, 1) GSA(1, t + 1, 1) GSA(2, t + 2, 1) GSA(3, t + 3, 1)
  }
  GSA(0, t, 0) GSA(1, t + 1, 0) GSA(2, t + 2, 0) GSA(3, t + 3, 0)

  // epilogue: C/D map col=lane&15, row=(lane>>4)*4+reg
  const int colg = bn * 32 + wc * 16 + lrow;
  const int rowb = bm * 64 + wr * 32 + ((l >> 4) << 2);
  const float bv = bias[colg];
#pragma unroll
  for (int fa = 0; fa < 2; ++fa)
#pragma unroll
    for (int r = 0; r < 4; ++r) {
      float v = (fa ? acc1 : acc0)[r] + bv;
      v = v > 0.f ? v : 0.f;
      Y[(size_t)(rowb + fa * 16 + r) * N + colg] = f2bf(v);
    }
}

// ================= K2: gemm2 (32x32 tile) + out init =================
#define GI(s, t) { \
  const size_t ab = (size_t)(t) * 128; const int wf = (t) * 64; \
  pa0_##s = *(const s16x8*)(agp0 + ab); \
  pw0_##s = *(const f32x4*)(wgp + wf); pw1_##s = *(const f32x4*)(wgp + wf + 4); }

#define GS(s, t, DOLOAD) { \
  char* buf = lds[(s) & 1]; \
  *(s16x8*)(buf + ABYTES + bwo0) = pack8(pw0_##s, pw1_##s); \
  *(s16x8*)(buf + awo0) = pa0_##s; \
  asm volatile("s_waitcnt lgkmcnt(0)" ::: "memory"); \
  __builtin_amdgcn_s_barrier(); \
  asm volatile("" ::: "memory"); \
  if (DOLOAD) GI(s, (t) + 4) \
  __builtin_amdgcn_s_setprio(1); \
  _Pragma("unroll") \
  for (int ks = 0; ks < 2; ++ks) { \
    const int kq = ((ks << 6) | lk) ^ sw; \
    s16x8 a0 = *(const s16x8*)(buf + aoff + kq); \
    s16x8 b0 = *(const s16x8*)(buf + ABYTES + boff + kq); \
    acc0 = __builtin_amdgcn_mfma_f32_16x16x32_bf16(a0, b0, acc0, 0, 0, 0); \
  } \
  __builtin_amdgcn_s_setprio(0); }

__global__ __launch_bounds__(256) void k_gemm2(
    const u16* __restrict__ A, const float* __restrict__ W,
    const float* __restrict__ bias, u16* __restrict__ Y,
    const int* __restrict__ cells, const float* __restrict__ O1,
    float* __restrict__ out) {
  constexpr int K = 2048, N = 1024;
  constexpr int ABYTES = 32 * 128;
  __shared__ char lds[2][ABYTES + 4096];
  const int tid = threadIdx.x;

  // out init (ready before k_head launches)
  if (blockIdx.x < 2) out[blockIdx.x * 256 + tid] = O1[cells[blockIdx.x * 256 + tid]];

  const int w = tid >> 6, l = tid & 63;
  const int wr = w >> 1, wc = w & 1;
  const int lrow = l & 15;
  const int lk = (l >> 4) << 4;
  const int sw = (lrow & 7) << 4;

  const int wgid = (blockIdx.x & 7) * 64 + (blockIdx.x >> 3);
  const int bn = wgid >> 4, bm = wgid & 15;

  const size_t K2 = (size_t)K * 2;
  const char* Ag = (const char*)A + (size_t)bm * 32 * K2;
  const float* Wg = W + (size_t)bn * 32 * K;

  const int o0 = tid * 16;
  const int ar0 = o0 >> 7, ac0 = o0 & 127;
  const char* agp0 = Ag + (size_t)ar0 * K2 + ac0;
  const int awo0 = (ar0 << 7) + (ac0 ^ ((ar0 & 7) << 4));

  const int br = tid >> 3, bq = tid & 7;
  const float* wgp = Wg + (size_t)br * K + bq * 8;
  const int bwo0 = (br << 7) + ((bq * 16) ^ ((br & 7) << 4));

  const int aoff = (wr * 16 + lrow) * 128;
  const int boff = (wc * 16 + lrow) * 128;

  f32x4 acc0 = {};
  s16x8 pa0_0, pa0_1, pa0_2, pa0_3;
  f32x4 pw0_0, pw1_0, pw0_1, pw1_1, pw0_2, pw1_2, pw0_3, pw1_3;

  GI(0, 0) GI(1, 1) GI(2, 2) GI(3, 3)
  constexpr int NT = 32;
  int t = 0;
  for (; t < NT - 4; t += 4) {
    GS(0, t, 1) GS(1, t + 1, 1) GS(2, t + 2, 1) GS(3, t + 3, 1)
  }
  GS(0, t, 0) GS(1, t + 1, 0) GS(2, t + 2, 0) GS(3, t + 3, 0)

  const int colg = bn * 32 + wc * 16 + lrow;
  const int rowb = bm * 32 + wr * 16 + ((l >> 4) << 2);
  const float bv = bias[colg];
#pragma unroll
  for (int r = 0; r < 4; ++r) {
    float v = acc0[r] + bv;
    v = v > 0.f ? v : 0.f;
    Y[(size_t)(rowb + r) * N + colg] = f2bf(v);
  }
}

// ================= K3: head; atomicAdd partials into out =============
#define H_ISSUE(S, ch) { \
  const float* src = hsrc + (ch) * 256; \
  q0_##S = *(const f32x4*)(src);      q1_##S = *(const f32x4*)(src + 4); \
  q2_##S = *(const f32x4*)(src + 8);  q3_##S = *(const f32x4*)(src + 12); \
  q4_##S = *(const f32x4*)(src + 16); q5_##S = *(const f32x4*)(src + 20); \
  q6_##S = *(const f32x4*)(src + 24); q7_##S = *(const f32x4*)(src + 28); }

#define H_WRITE(S, ch) { \
  char* dst = lbuf[(ch) & 1] + (hrow << 9); \
  *(s16x8*)(dst + ((hcb + 0)  ^ hswz)) = pack8(q0_##S, q1_##S); \
  *(s16x8*)(dst + ((hcb + 16) ^ hswz)) = pack8(q2_##S, q3_##S); \
  *(s16x8*)(dst + ((hcb + 32) ^ hswz)) = pack8(q4_##S, q5_##S); \
  *(s16x8*)(dst + ((hcb + 48) ^ hswz)) = pack8(q6_##S, q7_##S); }

#define H_SYNC { \
  asm volatile("s_waitcnt lgkmcnt(0)" ::: "memory"); \
  __builtin_amdgcn_s_barrier(); \
  asm volatile("" ::: "memory"); }

#define H_MFMA(ch) { \
  const char* bb = lbuf[(ch) & 1]; \
  s16x8 bv0 = *(const s16x8*)(bb + ((0 * 16 + lrow) << 9) + kboff); \
  s16x8 bv1 = *(const s16x8*)(bb + ((1 * 16 + lrow) << 9) + kboff); \
  s16x8 bv2 = *(const s16x8*)(bb + ((2 * 16 + lrow) << 9) + kboff); \
  s16x8 bv3 = *(const s16x8*)(bb + ((3 * 16 + lrow) << 9) + kboff); \
  s16x8 av0 = *(const s16x8*)(ap0 + (ch) * 256); \
  s16x8 av1 = *(const s16x8*)(ap1 + (ch) * 256); \
  __builtin_amdgcn_s_setprio(1); \
  acc[0][0] = __builtin_amdgcn_mfma_f32_16x16x32_bf16(av0, bv0, acc[0][0], 0, 0, 0); \
  acc[0][1] = __builtin_amdgcn_mfma_f32_16x16x32_bf16(av0, bv1, acc[0][1], 0, 0, 0); \
  acc[0][2] = __builtin_amdgcn_mfma_f32_16x16x32_bf16(av0, bv2, acc[0][2], 0, 0, 0); \
  acc[0][3] = __builtin_amdgcn_mfma_f32_16x16x32_bf16(av0, bv3, acc[0][3], 0, 0, 0); \
  acc[1][0] = __builtin_amdgcn_mfma_f32_16x16x32_bf16(av1, bv0, acc[1][0], 0, 0, 0); \
  acc[1][1] = __builtin_amdgcn_mfma_f32_16x16x32_bf16(av1, bv1, acc[1][1], 0, 0, 0); \
  acc[1][2] = __builtin_amdgcn_mfma_f32_16x16x32_bf16(av1, bv2, acc[1][2], 0, 0, 0); \
  acc[1][3] = __builtin_amdgcn_mfma_f32_16x16x32_bf16(av1, bv3, acc[1][3], 0, 0, 0); \
  __builtin_amdgcn_s_setprio(0); }

__global__ __launch_bounds__(512) void k_head(
    const int* __restrict__ cells, const u16* __restrict__ y2b,
    const float* __restrict__ L0, const float* __restrict__ O0,
    const float* __restrict__ L1, float* __restrict__ out) {
  __shared__ int slist[544];
  __shared__ int scnt;
  __shared__ float red[8][2048];      // 64 KB
  __shared__ char lbuf[2][32768];     // 64 KB
  const int tid = threadIdx.x;
  const int c = blockIdx.x >> 3, rt = blockIdx.x & 7;
  if (tid == 0) scnt = 0;
  __syncthreads();
  for (int i = tid; i < BATCH; i += 512)
    if (cells[i] == c) slist[atomicAdd(&scnt, 1)] = i;
  __syncthreads();
  const int ns = scnt;
  if (ns == 0) return;
  const int npad = (ns + 31) & ~31;
  for (int i = ns + tid; i < npad; i += 512) slist[i] = slist[0];
  __syncthreads();

  const int w = tid >> 6, l = tid & 63;
  const int lrow = l & 15;
  const int r0 = rt * 64;
  const float* L0c = L0 + ((size_t)c * N2 + r0) * N1;
  const int hrow = tid >> 3;
  const int hcb = (tid & 7) * 64;
  const int hswz = (hrow & 7) << 4;
  const float* hsrc = L0c + (size_t)hrow * N1 + (tid & 7) * 32;
  const int kboff = ((w * 64 + ((l >> 4) << 4)) ^ ((lrow & 7) << 4));

  f32x4 q0_A, q1_A, q2_A, q3_A, q4_A, q5_A, q6_A, q7_A;
  f32x4 q0_B, q1_B, q2_B, q3_B, q4_B, q5_B, q6_B, q7_B;

  for (int cb = 0; cb < npad; cb += 32) {
    const u16* ap0 = y2b + (size_t)slist[cb + lrow] * N1 + w * 32 + ((l >> 4) << 3);
    const u16* ap1 = y2b + (size_t)slist[cb + 16 + lrow] * N1 + w * 32 + ((l >> 4) << 3);
    f32x4 acc[2][4] = {};
    H_ISSUE(A, 0)
    H_WRITE(A, 0)
    H_ISSUE(B, 1)
    H_SYNC
    H_MFMA(0)
    H_WRITE(B, 1)
    H_ISSUE(A, 2)
    H_SYNC
    H_MFMA(1)
    H_WRITE(A, 2)
    H_ISSUE(B, 3)
    H_SYNC
    H_MFMA(2)
    H_WRITE(B, 3)
    H_SYNC
    H_MFMA(3)

    __syncthreads();
#pragma unroll
    for (int h = 0; h < 2; ++h)
#pragma unroll
      for (int fb = 0; fb < 4; ++fb)
#pragma unroll
        for (int r = 0; r < 4; ++r) {
          const int s0 = h * 16 + (l >> 4) * 4 + r;
          red[w][s0 * 64 + fb * 16 + lrow] = acc[h][fb][r];
        }
    __syncthreads();
    {
      const int s = tid >> 4;
      const int rq = (tid & 15) * 4;
      if (cb + s < ns) {
        float p = 0.f;
#pragma unroll
        for (int j = 0; j < 4; ++j) {
          const int r = rq + j, e = s * 64 + r;
          float v = red[0][e] + red[1][e] + red[2][e] + red[3][e] +
                    red[4][e] + red[5][e] + red[6][e] + red[7][e] +
                    O0[(size_t)c * N2 + r0 + r];
          v = v > 0.f ? v : 0.f;
          p += v * L1[(size_t)c * N2 + r0 + r];
        }
#pragma unroll
        for (int off = 8; off; off >>= 1) p += __shfl_xor(p, off, 16);
        if ((tid & 15) == 0) atomicAdd(&out[slist[cb + s]], p);
      }
    }
  }
}

// ---------------- launch ----------------
extern "C" void kernel_launch(void* const* d_in, const int* in_sizes, int n_in,
                              void* d_out, int out_size, void* d_ws, size_t ws_size,
                              hipStream_t stream) {
  const int*   pairs  = (const int*)d_in[0];
  const int*   cells  = (const int*)d_in[1];
  const float* attrs  = (const float*)d_in[2];
  const float* h_drug = (const float*)d_in[3];
  const float* W0     = (const float*)d_in[4];
  const float* b0     = (const float*)d_in[5];
  const float* W1     = (const float*)d_in[6];
  const float* b1     = (const float*)d_in[7];
  const float* L0     = (const float*)d_in[8];
  const float* O0     = (const float*)d_in[9];
  const float* L1     = (const float*)d_in[10];
  const float* O1     = (const float*)d_in[11];
  float* out = (float*)d_out;

  char* ws = (char*)d_ws;
  u16* y1b = (u16*)(ws);                 // 2 MB  512x2048 bf16
  u16* y2b = (u16*)(ws + (2u << 20));    // 1 MB  512x1024 bf16

  k_fgemm1<<<512, 256, 0, stream>>>(pairs, attrs, h_drug, W0, b0, y1b);
  k_gemm2<<<512, 256, 0, stream>>>(y1b, W1, b1, y2b, cells, O1, out);
  k_head<<<256, 512, 0, stream>>>(cells, y2b, L0, O0, L1, out);
}

// Round 10
// 48.256 us; speedup vs baseline: 1.1381x; 1.1381x over previous
//
#include <hip/hip_runtime.h>

typedef short s16x8 __attribute__((ext_vector_type(8)));
typedef float f32x4 __attribute__((ext_vector_type(4)));
typedef unsigned short u16;

#define BATCH 512
#define HD    1023
#define K0    2048
#define N0    2048
#define N1    1024
#define N2    512

// round-to-nearest-even f32 -> bf16 (scalar path)
__device__ __forceinline__ u16 f2bf(float f) {
  unsigned u = __builtin_bit_cast(unsigned, f);
  unsigned r = (u + 0x7fffu + ((u >> 16) & 1u)) >> 16;
  return (u16)r;
}

// packed RNE convert: 8 f32 -> 8 bf16 in 4 VALU ops
__device__ __forceinline__ s16x8 pack8(f32x4 a, f32x4 b) {
  union { unsigned u[4]; s16x8 v; } r;
  asm("v_cvt_pk_bf16_f32 %0, %1, %2" : "=v"(r.u[0]) : "v"(a[0]), "v"(a[1]));
  asm("v_cvt_pk_bf16_f32 %0, %1, %2" : "=v"(r.u[1]) : "v"(a[2]), "v"(a[3]));
  asm("v_cvt_pk_bf16_f32 %0, %1, %2" : "=v"(r.u[2]) : "v"(b[0]), "v"(b[1]));
  asm("v_cvt_pk_bf16_f32 %0, %1, %2" : "=v"(r.u[3]) : "v"(b[2]), "v"(b[3]));
  return r.v;
}

// ================= K0: prep — gather x, convert W0/W1 to bf16, init out ==========
__global__ __launch_bounds__(256) void k_prep(
    const int* __restrict__ pairs, const float* __restrict__ attrs,
    const float* __restrict__ h_drug, const float* __restrict__ W0,
    const float* __restrict__ W1, const int* __restrict__ cells,
    const float* __restrict__ O1, u16* __restrict__ xb,
    u16* __restrict__ w0b, u16* __restrict__ w1b, float* __restrict__ out) {
  const int bid = blockIdx.x, tid = threadIdx.x;
  if (bid < 512) {
    const int b = bid;
    const float* h0 = h_drug + (size_t)pairs[2 * b] * HD;
    const float* h1 = h_drug + (size_t)pairs[2 * b + 1] * HD;
    u16* xr = xb + (size_t)b * K0;
    for (int i = tid; i < HD; i += 256) {
      xr[i] = f2bf(h0[i]);
      xr[1024 + i] = f2bf(h1[i]);
    }
    if (tid == 0) {
      xr[1023] = f2bf(attrs[4 * b + 1]);
      xr[2047] = f2bf(attrs[4 * b + 3]);
      out[b] = O1[cells[b]];
    }
  } else if (bid < 1536) {
    const size_t e = ((size_t)(bid - 512) * 256 + tid) * 16;
    f32x4 a = *(const f32x4*)(W0 + e),     b2 = *(const f32x4*)(W0 + e + 4);
    f32x4 c = *(const f32x4*)(W0 + e + 8), d  = *(const f32x4*)(W0 + e + 12);
    *(s16x8*)(w0b + e)     = pack8(a, b2);
    *(s16x8*)(w0b + e + 8) = pack8(c, d);
  } else {
    const size_t e = ((size_t)(bid - 1536) * 256 + tid) * 16;
    f32x4 a = *(const f32x4*)(W1 + e),     b2 = *(const f32x4*)(W1 + e + 4);
    f32x4 c = *(const f32x4*)(W1 + e + 8), d  = *(const f32x4*)(W1 + e + 12);
    *(s16x8*)(w1b + e)     = pack8(a, b2);
    *(s16x8*)(w1b + e + 8) = pack8(c, d);
  }
}

// ================= bf16 GEMM (A bf16, B bf16): Y = relu(A*B^T + bias) ============
// Tile BM x 32, BK=64, 4 waves 2x2, grid 512 (2 blocks/CU), 4-deep reg prefetch,
// T2 LDS XOR swizzle, raw s_barrier + lgkmcnt(0) only (T4), setprio (T5).
#define GI(s, t) { \
  pa0_##s = *(const s16x8*)(agp0 + (size_t)(t) * 128); \
  if constexpr (AF == 2) pa1_##s = *(const s16x8*)(agp1 + (size_t)(t) * 128); \
  pb_##s = *(const s16x8*)(bgp0 + (size_t)(t) * 128); }

#define GS(s, t, DOLOAD) { \
  char* buf = lds[(s) & 1]; \
  *(s16x8*)(buf + awo0) = pa0_##s; \
  if constexpr (AF == 2) *(s16x8*)(buf + awo1) = pa1_##s; \
  *(s16x8*)(buf + ABYTES + bwo0) = pb_##s; \
  asm volatile("s_waitcnt lgkmcnt(0)" ::: "memory"); \
  __builtin_amdgcn_s_barrier(); \
  asm volatile("" ::: "memory"); \
  if (DOLOAD) GI(s, (t) + 4) \
  __builtin_amdgcn_s_setprio(1); \
  _Pragma("unroll") \
  for (int ks = 0; ks < 2; ++ks) { \
    const int kq = ((ks << 6) | lk) ^ sw; \
    s16x8 a0 = *(const s16x8*)(buf + aoff + kq); \
    s16x8 b0 = *(const s16x8*)(buf + ABYTES + boff + kq); \
    acc0 = __builtin_amdgcn_mfma_f32_16x16x32_bf16(a0, b0, acc0, 0, 0, 0); \
    if constexpr (AF == 2) { \
      s16x8 a1 = *(const s16x8*)(buf + aoff + 2048 + kq); \
      acc1 = __builtin_amdgcn_mfma_f32_16x16x32_bf16(a1, b0, acc1, 0, 0, 0); \
    } \
  } \
  __builtin_amdgcn_s_setprio(0); }

template <int BM, int N>
__global__ __launch_bounds__(256) void k_gemm(
    const u16* __restrict__ A, const u16* __restrict__ B,
    const float* __restrict__ bias, u16* __restrict__ Y) {
  constexpr int K = 2048;
  constexpr int AF = BM / 32;
  constexpr int ABYTES = BM * 128;
  constexpr int NBMSH = (BM == 64) ? 3 : 4;   // log2(512/BM)
  __shared__ char lds[2][ABYTES + 4096];
  const int tid = threadIdx.x;
  const int w = tid >> 6, l = tid & 63;
  const int wr = w >> 1, wc = w & 1;
  const int lrow = l & 15;
  const int lk = (l >> 4) << 4;
  const int sw = (lrow & 7) << 4;

  // XCD swizzle (grid 512): each XCD owns 64 contiguous wgids
  const int wgid = (blockIdx.x & 7) * 64 + (blockIdx.x >> 3);
  const int bn = wgid >> NBMSH, bm = wgid & ((1 << NBMSH) - 1);

  const size_t K2 = (size_t)K * 2;
  const char* Ag = (const char*)A + (size_t)bm * BM * K2;
  const char* Bg = (const char*)B + (size_t)(bn * 32) * K2;

  // A staging: BM rows x 128B; thread covers tile byte tid*16 (+4096 if BM=64)
  const int o0 = tid * 16;
  const int ar0 = o0 >> 7, ac0 = o0 & 127;
  const char* agp0 = Ag + (size_t)ar0 * K2 + ac0;
  const int awo0 = (ar0 << 7) + (ac0 ^ ((ar0 & 7) << 4));
  const int o1 = o0 + 4096;
  const int ar1 = o1 >> 7, ac1 = o1 & 127;
  const char* agp1 = Ag + (size_t)ar1 * K2 + ac1;   // used only if AF==2
  const int awo1 = (ar1 << 7) + (ac1 ^ ((ar1 & 7) << 4));

  // B staging: 32 rows x 128B; thread covers byte tid*16
  const char* bgp0 = Bg + (size_t)ar0 * K2 + ac0;
  const int bwo0 = awo0;

  const int aoff = (wr * (BM / 2) + lrow) * 128;
  const int boff = (wc * 16 + lrow) * 128;

  f32x4 acc0 = {}, acc1 = {};
  s16x8 pa0_0, pa0_1, pa0_2, pa0_3;
  s16x8 pa1_0, pa1_1, pa1_2, pa1_3;
  s16x8 pb_0, pb_1, pb_2, pb_3;

  GI(0, 0) GI(1, 1) GI(2, 2) GI(3, 3)
  constexpr int NT = 32;  // K/64
  int t = 0;
  for (; t < NT - 4; t += 4) {
    GS(0, t, 1) GS(1, t + 1, 1) GS(2, t + 2, 1) GS(3, t + 3, 1)
  }
  GS(0, t, 0) GS(1, t + 1, 0) GS(2, t + 2, 0) GS(3, t + 3, 0)

  // epilogue: C/D map col=lane&15, row=(lane>>4)*4+reg
  const int colg = bn * 32 + wc * 16 + lrow;
  const int rowb = bm * BM + wr * (BM / 2) + ((l >> 4) << 2);
  const float bv = bias[colg];
#pragma unroll
  for (int fa = 0; fa < AF; ++fa)
#pragma unroll
    for (int r = 0; r < 4; ++r) {
      float v = (fa ? acc1 : acc0)[r] + bv;
      v = v > 0.f ? v : 0.f;
      Y[(size_t)(rowb + fa * 16 + r) * N + colg] = f2bf(v);
    }
}

// ================= K3: head; atomicAdd partials into out =============
#define H_ISSUE(S, ch) { \
  const float* src = hsrc + (ch) * 256; \
  q0_##S = *(const f32x4*)(src);      q1_##S = *(const f32x4*)(src + 4); \
  q2_##S = *(const f32x4*)(src + 8);  q3_##S = *(const f32x4*)(src + 12); \
  q4_##S = *(const f32x4*)(src + 16); q5_##S = *(const f32x4*)(src + 20); \
  q6_##S = *(const f32x4*)(src + 24); q7_##S = *(const f32x4*)(src + 28); }

#define H_WRITE(S, ch) { \
  char* dst = lbuf[(ch) & 1] + (hrow << 9); \
  *(s16x8*)(dst + ((hcb + 0)  ^ hswz)) = pack8(q0_##S, q1_##S); \
  *(s16x8*)(dst + ((hcb + 16) ^ hswz)) = pack8(q2_##S, q3_##S); \
  *(s16x8*)(dst + ((hcb + 32) ^ hswz)) = pack8(q4_##S, q5_##S); \
  *(s16x8*)(dst + ((hcb + 48) ^ hswz)) = pack8(q6_##S, q7_##S); }

#define H_SYNC { \
  asm volatile("s_waitcnt lgkmcnt(0)" ::: "memory"); \
  __builtin_amdgcn_s_barrier(); \
  asm volatile("" ::: "memory"); }

#define H_MFMA(ch) { \
  const char* bb = lbuf[(ch) & 1]; \
  s16x8 bv0 = *(const s16x8*)(bb + ((0 * 16 + lrow) << 9) + kboff); \
  s16x8 bv1 = *(const s16x8*)(bb + ((1 * 16 + lrow) << 9) + kboff); \
  s16x8 bv2 = *(const s16x8*)(bb + ((2 * 16 + lrow) << 9) + kboff); \
  s16x8 bv3 = *(const s16x8*)(bb + ((3 * 16 + lrow) << 9) + kboff); \
  s16x8 av0 = *(const s16x8*)(ap0 + (ch) * 256); \
  s16x8 av1 = *(const s16x8*)(ap1 + (ch) * 256); \
  __builtin_amdgcn_s_setprio(1); \
  acc[0][0] = __builtin_amdgcn_mfma_f32_16x16x32_bf16(av0, bv0, acc[0][0], 0, 0, 0); \
  acc[0][1] = __builtin_amdgcn_mfma_f32_16x16x32_bf16(av0, bv1, acc[0][1], 0, 0, 0); \
  acc[0][2] = __builtin_amdgcn_mfma_f32_16x16x32_bf16(av0, bv2, acc[0][2], 0, 0, 0); \
  acc[0][3] = __builtin_amdgcn_mfma_f32_16x16x32_bf16(av0, bv3, acc[0][3], 0, 0, 0); \
  acc[1][0] = __builtin_amdgcn_mfma_f32_16x16x32_bf16(av1, bv0, acc[1][0], 0, 0, 0); \
  acc[1][1] = __builtin_amdgcn_mfma_f32_16x16x32_bf16(av1, bv1, acc[1][1], 0, 0, 0); \
  acc[1][2] = __builtin_amdgcn_mfma_f32_16x16x32_bf16(av1, bv2, acc[1][2], 0, 0, 0); \
  acc[1][3] = __builtin_amdgcn_mfma_f32_16x16x32_bf16(av1, bv3, acc[1][3], 0, 0, 0); \
  __builtin_amdgcn_s_setprio(0); }

__global__ __launch_bounds__(512) void k_head(
    const int* __restrict__ cells, const u16* __restrict__ y2b,
    const float* __restrict__ L0, const float* __restrict__ O0,
    const float* __restrict__ L1, float* __restrict__ out) {
  __shared__ int slist[544];
  __shared__ int scnt;
  __shared__ float red[8][2048];      // 64 KB
  __shared__ char lbuf[2][32768];     // 64 KB
  const int tid = threadIdx.x;
  const int c = blockIdx.x >> 3, rt = blockIdx.x & 7;
  if (tid == 0) scnt = 0;
  __syncthreads();
  for (int i = tid; i < BATCH; i += 512)
    if (cells[i] == c) slist[atomicAdd(&scnt, 1)] = i;
  __syncthreads();
  const int ns = scnt;
  if (ns == 0) return;
  const int npad = (ns + 31) & ~31;
  for (int i = ns + tid; i < npad; i += 512) slist[i] = slist[0];
  __syncthreads();

  const int w = tid >> 6, l = tid & 63;
  const int lrow = l & 15;
  const int r0 = rt * 64;
  const float* L0c = L0 + ((size_t)c * N2 + r0) * N1;
  const int hrow = tid >> 3;
  const int hcb = (tid & 7) * 64;
  const int hswz = (hrow & 7) << 4;
  const float* hsrc = L0c + (size_t)hrow * N1 + (tid & 7) * 32;
  const int kboff = ((w * 64 + ((l >> 4) << 4)) ^ ((lrow & 7) << 4));

  f32x4 q0_A, q1_A, q2_A, q3_A, q4_A, q5_A, q6_A, q7_A;
  f32x4 q0_B, q1_B, q2_B, q3_B, q4_B, q5_B, q6_B, q7_B;

  for (int cb = 0; cb < npad; cb += 32) {
    const u16* ap0 = y2b + (size_t)slist[cb + lrow] * N1 + w * 32 + ((l >> 4) << 3);
    const u16* ap1 = y2b + (size_t)slist[cb + 16 + lrow] * N1 + w * 32 + ((l >> 4) << 3);
    f32x4 acc[2][4] = {};
    H_ISSUE(A, 0)
    H_WRITE(A, 0)
    H_ISSUE(B, 1)
    H_SYNC
    H_MFMA(0)
    H_WRITE(B, 1)
    H_ISSUE(A, 2)
    H_SYNC
    H_MFMA(1)
    H_WRITE(A, 2)
    H_ISSUE(B, 3)
    H_SYNC
    H_MFMA(2)
    H_WRITE(B, 3)
    H_SYNC
    H_MFMA(3)

    __syncthreads();
#pragma unroll
    for (int h = 0; h < 2; ++h)
#pragma unroll
      for (int fb = 0; fb < 4; ++fb)
#pragma unroll
        for (int r = 0; r < 4; ++r) {
          const int s0 = h * 16 + (l >> 4) * 4 + r;
          red[w][s0 * 64 + fb * 16 + lrow] = acc[h][fb][r];
        }
    __syncthreads();
    {
      const int s = tid >> 4;
      const int rq = (tid & 15) * 4;
      if (cb + s < ns) {
        float p = 0.f;
#pragma unroll
        for (int j = 0; j < 4; ++j) {
          const int r = rq + j, e = s * 64 + r;
          float v = red[0][e] + red[1][e] + red[2][e] + red[3][e] +
                    red[4][e] + red[5][e] + red[6][e] + red[7][e] +
                    O0[(size_t)c * N2 + r0 + r];
          v = v > 0.f ? v : 0.f;
          p += v * L1[(size_t)c * N2 + r0 + r];
        }
#pragma unroll
        for (int off = 8; off; off >>= 1) p += __shfl_xor(p, off, 16);
        if ((tid & 15) == 0) atomicAdd(&out[slist[cb + s]], p);
      }
    }
  }
}

// ---------------- launch ----------------
extern "C" void kernel_launch(void* const* d_in, const int* in_sizes, int n_in,
                              void* d_out, int out_size, void* d_ws, size_t ws_size,
                              hipStream_t stream) {
  const int*   pairs  = (const int*)d_in[0];
  const int*   cells  = (const int*)d_in[1];
  const float* attrs  = (const float*)d_in[2];
  const float* h_drug = (const float*)d_in[3];
  const float* W0     = (const float*)d_in[4];
  const float* b0     = (const float*)d_in[5];
  const float* W1     = (const float*)d_in[6];
  const float* b1     = (const float*)d_in[7];
  const float* L0     = (const float*)d_in[8];
  const float* O0     = (const float*)d_in[9];
  const float* L1     = (const float*)d_in[10];
  const float* O1     = (const float*)d_in[11];
  float* out = (float*)d_out;

  char* ws = (char*)d_ws;
  u16* xb  = (u16*)(ws);                  // 2 MB  512x2048 bf16
  u16* w0b = (u16*)(ws + (2u  << 20));    // 8 MB  2048x2048 bf16
  u16* w1b = (u16*)(ws + (10u << 20));    // 4 MB  1024x2048 bf16
  u16* y1b = (u16*)(ws + (14u << 20));    // 2 MB  512x2048 bf16
  u16* y2b = (u16*)(ws + (16u << 20));    // 1 MB  512x1024 bf16

  k_prep<<<2048, 256, 0, stream>>>(pairs, attrs, h_drug, W0, W1, cells, O1,
                                   xb, w0b, w1b, out);
  k_gemm<64, N0><<<512, 256, 0, stream>>>(xb, w0b, b0, y1b);
  k_gemm<32, N1><<<512, 256, 0, stream>>>(y1b, w1b, b1, y2b);
  k_head<<<256, 512, 0, stream>>>(cells, y2b, L0, O0, L1, out);
}

// Round 11
// 46.221 us; speedup vs baseline: 1.1882x; 1.0440x over previous
//
#include <hip/hip_runtime.h>

typedef short s16x8 __attribute__((ext_vector_type(8)));
typedef float f32x4 __attribute__((ext_vector_type(4)));
typedef unsigned short u16;

#define BATCH 512
#define HD    1023
#define K0    2048
#define N0    2048
#define N1    1024
#define N2    512

// round-to-nearest-even f32 -> bf16 (scalar path)
__device__ __forceinline__ u16 f2bf(float f) {
  unsigned u = __builtin_bit_cast(unsigned, f);
  unsigned r = (u + 0x7fffu + ((u >> 16) & 1u)) >> 16;
  return (u16)r;
}

// packed RNE convert: 8 f32 -> 8 bf16 in 4 VALU ops
__device__ __forceinline__ s16x8 pack8(f32x4 a, f32x4 b) {
  union { unsigned u[4]; s16x8 v; } r;
  asm("v_cvt_pk_bf16_f32 %0, %1, %2" : "=v"(r.u[0]) : "v"(a[0]), "v"(a[1]));
  asm("v_cvt_pk_bf16_f32 %0, %1, %2" : "=v"(r.u[1]) : "v"(a[2]), "v"(a[3]));
  asm("v_cvt_pk_bf16_f32 %0, %1, %2" : "=v"(r.u[2]) : "v"(b[0]), "v"(b[1]));
  asm("v_cvt_pk_bf16_f32 %0, %1, %2" : "=v"(r.u[3]) : "v"(b[2]), "v"(b[3]));
  return r.v;
}

// ================= K0: prep — gather x, convert W0 to bf16, init out ==========
__global__ __launch_bounds__(256) void k_prep(
    const int* __restrict__ pairs, const float* __restrict__ attrs,
    const float* __restrict__ h_drug, const float* __restrict__ W0,
    const int* __restrict__ cells, const float* __restrict__ O1,
    u16* __restrict__ xb, u16* __restrict__ w0b, float* __restrict__ out) {
  const int bid = blockIdx.x, tid = threadIdx.x;
  if (bid < 512) {
    const int b = bid;
    const float* h0 = h_drug + (size_t)pairs[2 * b] * HD;
    const float* h1 = h_drug + (size_t)pairs[2 * b + 1] * HD;
    u16* xr = xb + (size_t)b * K0;
    for (int i = tid; i < HD; i += 256) {
      xr[i] = f2bf(h0[i]);
      xr[1024 + i] = f2bf(h1[i]);
    }
    if (tid == 0) {
      xr[1023] = f2bf(attrs[4 * b + 1]);
      xr[2047] = f2bf(attrs[4 * b + 3]);
      out[b] = O1[cells[b]];
    }
  } else {
    const size_t e = ((size_t)(bid - 512) * 256 + tid) * 16;
    f32x4 a = *(const f32x4*)(W0 + e),     b2 = *(const f32x4*)(W0 + e + 4);
    f32x4 c = *(const f32x4*)(W0 + e + 8), d  = *(const f32x4*)(W0 + e + 12);
    *(s16x8*)(w0b + e)     = pack8(a, b2);
    *(s16x8*)(w0b + e + 8) = pack8(c, d);
  }
}

// ================= K1: gemm1 — 64x64 tile, 8 waves, grid 256 + W1 riders =========
// y1 = relu(X[512x2048] * W0[2048x2048]^T + b0) -> bf16 (all operands bf16).
// 8 waves as 2(m) x 4(n); wave tile 32x16; 4 MFMA / K-tile / wave; NT=32; 4-deep
// register prefetch; T2 LDS swizzle; raw s_barrier + lgkmcnt(0) only (T4); T5.
// Blocks 256..767 convert W1 f32 -> bf16 (ready before gemm2 launches).
#define GI1(s, t) { \
  pa_##s = *(const s16x8*)(agp0 + (size_t)(t) * 128); \
  pb_##s = *(const s16x8*)(bgp0 + (size_t)(t) * 128); }

#define GS1(s, t, DOLOAD) { \
  char* buf = lds[(s) & 1]; \
  *(s16x8*)(buf + awo0) = pa_##s; \
  *(s16x8*)(buf + 8192 + awo0) = pb_##s; \
  asm volatile("s_waitcnt lgkmcnt(0)" ::: "memory"); \
  __builtin_amdgcn_s_barrier(); \
  asm volatile("" ::: "memory"); \
  if (DOLOAD) GI1(s, (t) + 4) \
  __builtin_amdgcn_s_setprio(1); \
  _Pragma("unroll") \
  for (int ks = 0; ks < 2; ++ks) { \
    const int kq = ((ks << 6) | lk) ^ sw; \
    s16x8 a0 = *(const s16x8*)(buf + aoff + kq); \
    s16x8 a1 = *(const s16x8*)(buf + aoff + 2048 + kq); \
    s16x8 b0 = *(const s16x8*)(buf + 8192 + boff + kq); \
    acc0 = __builtin_amdgcn_mfma_f32_16x16x32_bf16(a0, b0, acc0, 0, 0, 0); \
    acc1 = __builtin_amdgcn_mfma_f32_16x16x32_bf16(a1, b0, acc1, 0, 0, 0); \
  } \
  __builtin_amdgcn_s_setprio(0); }

__global__ __launch_bounds__(512) void k_gemm1(
    const u16* __restrict__ A, const u16* __restrict__ B,
    const float* __restrict__ bias, u16* __restrict__ Y,
    const float* __restrict__ W1f, u16* __restrict__ w1b) {
  constexpr int K = 2048, N = 2048;
  if (blockIdx.x >= 256) {  // W1 conversion riders
    const size_t e = (((size_t)blockIdx.x - 256) * 512 + threadIdx.x) * 8;
    f32x4 a = *(const f32x4*)(W1f + e), b2 = *(const f32x4*)(W1f + e + 4);
    *(s16x8*)(w1b + e) = pack8(a, b2);
    return;
  }
  __shared__ char lds[2][16384];  // A 8KB + B 8KB per buffer
  const int tid = threadIdx.x;
  const int w = tid >> 6, l = tid & 63;
  const int wr = w >> 2, wn = w & 3;
  const int lrow = l & 15;
  const int lk = (l >> 4) << 4;
  const int sw = (lrow & 7) << 4;

  // XCD swizzle (256 GEMM blocks): each XCD owns 32 contiguous wgids (4 bn x 8 bm)
  const int wgid = (blockIdx.x & 7) * 32 + (blockIdx.x >> 3);
  const int bn = wgid >> 3, bm = wgid & 7;

  const size_t K2 = (size_t)K * 2;
  const char* Ag = (const char*)A + (size_t)bm * 64 * K2;
  const char* Bg = (const char*)B + (size_t)bn * 64 * K2;

  // staging: 64 rows x 128B each; thread covers byte tid*16 of the tile
  const int o0 = tid * 16;
  const int ar0 = o0 >> 7, ac0 = o0 & 127;
  const char* agp0 = Ag + (size_t)ar0 * K2 + ac0;
  const char* bgp0 = Bg + (size_t)ar0 * K2 + ac0;
  const int awo0 = (ar0 << 7) + (ac0 ^ ((ar0 & 7) << 4));

  const int aoff = (wr * 32 + lrow) * 128;
  const int boff = (wn * 16 + lrow) * 128;

  f32x4 acc0 = {}, acc1 = {};
  s16x8 pa_0, pa_1, pa_2, pa_3;
  s16x8 pb_0, pb_1, pb_2, pb_3;

  GI1(0, 0) GI1(1, 1) GI1(2, 2) GI1(3, 3)
  constexpr int NT = 32;
  int t = 0;
  for (; t < NT - 4; t += 4) {
    GS1(0, t, 1) GS1(1, t + 1, 1) GS1(2, t + 2, 1) GS1(3, t + 3, 1)
  }
  GS1(0, t, 0) GS1(1, t + 1, 0) GS1(2, t + 2, 0) GS1(3, t + 3, 0)

  // epilogue: C/D map col=lane&15, row=(lane>>4)*4+reg
  const int colg = bn * 64 + wn * 16 + lrow;
  const int rowb = bm * 64 + wr * 32 + ((l >> 4) << 2);
  const float bv = bias[colg];
#pragma unroll
  for (int fa = 0; fa < 2; ++fa)
#pragma unroll
    for (int r = 0; r < 4; ++r) {
      float v = (fa ? acc1 : acc0)[r] + bv;
      v = v > 0.f ? v : 0.f;
      Y[(size_t)(rowb + fa * 16 + r) * N + colg] = f2bf(v);
    }
}

// ================= K2: gemm2 — 32x32 tile, grid 512 (v10 structure) ============
#define GI(s, t) { \
  pa0_##s = *(const s16x8*)(agp0 + (size_t)(t) * 128); \
  pb_##s = *(const s16x8*)(bgp0 + (size_t)(t) * 128); }

#define GS(s, t, DOLOAD) { \
  char* buf = lds[(s) & 1]; \
  *(s16x8*)(buf + awo0) = pa0_##s; \
  *(s16x8*)(buf + ABYTES + awo0) = pb_##s; \
  asm volatile("s_waitcnt lgkmcnt(0)" ::: "memory"); \
  __builtin_amdgcn_s_barrier(); \
  asm volatile("" ::: "memory"); \
  if (DOLOAD) GI(s, (t) + 4) \
  __builtin_amdgcn_s_setprio(1); \
  _Pragma("unroll") \
  for (int ks = 0; ks < 2; ++ks) { \
    const int kq = ((ks << 6) | lk) ^ sw; \
    s16x8 a0 = *(const s16x8*)(buf + aoff + kq); \
    s16x8 b0 = *(const s16x8*)(buf + ABYTES + boff + kq); \
    acc0 = __builtin_amdgcn_mfma_f32_16x16x32_bf16(a0, b0, acc0, 0, 0, 0); \
  } \
  __builtin_amdgcn_s_setprio(0); }

__global__ __launch_bounds__(256) void k_gemm2(
    const u16* __restrict__ A, const u16* __restrict__ B,
    const float* __restrict__ bias, u16* __restrict__ Y) {
  constexpr int K = 2048, N = 1024;
  constexpr int ABYTES = 32 * 128;
  __shared__ char lds[2][ABYTES + 4096];
  const int tid = threadIdx.x;
  const int w = tid >> 6, l = tid & 63;
  const int wr = w >> 1, wc = w & 1;
  const int lrow = l & 15;
  const int lk = (l >> 4) << 4;
  const int sw = (lrow & 7) << 4;

  // XCD swizzle (grid 512): each XCD owns 64 contiguous wgids
  const int wgid = (blockIdx.x & 7) * 64 + (blockIdx.x >> 3);
  const int bn = wgid >> 4, bm = wgid & 15;

  const size_t K2 = (size_t)K * 2;
  const char* Ag = (const char*)A + (size_t)bm * 32 * K2;
  const char* Bg = (const char*)B + (size_t)(bn * 32) * K2;

  const int o0 = tid * 16;
  const int ar0 = o0 >> 7, ac0 = o0 & 127;
  const char* agp0 = Ag + (size_t)ar0 * K2 + ac0;
  const char* bgp0 = Bg + (size_t)ar0 * K2 + ac0;
  const int awo0 = (ar0 << 7) + (ac0 ^ ((ar0 & 7) << 4));

  const int aoff = (wr * 16 + lrow) * 128;
  const int boff = (wc * 16 + lrow) * 128;

  f32x4 acc0 = {};
  s16x8 pa0_0, pa0_1, pa0_2, pa0_3;
  s16x8 pb_0, pb_1, pb_2, pb_3;

  GI(0, 0) GI(1, 1) GI(2, 2) GI(3, 3)
  constexpr int NT = 32;
  int t = 0;
  for (; t < NT - 4; t += 4) {
    GS(0, t, 1) GS(1, t + 1, 1) GS(2, t + 2, 1) GS(3, t + 3, 1)
  }
  GS(0, t, 0) GS(1, t + 1, 0) GS(2, t + 2, 0) GS(3, t + 3, 0)

  const int colg = bn * 32 + wc * 16 + lrow;
  const int rowb = bm * 32 + wr * 16 + ((l >> 4) << 2);
  const float bv = bias[colg];
#pragma unroll
  for (int r = 0; r < 4; ++r) {
    float v = acc0[r] + bv;
    v = v > 0.f ? v : 0.f;
    Y[(size_t)(rowb + r) * N + colg] = f2bf(v);
  }
}

// ================= K3: head; atomicAdd partials into out =============
#define H_ISSUE(S, ch) { \
  const float* src = hsrc + (ch) * 256; \
  q0_##S = *(const f32x4*)(src);      q1_##S = *(const f32x4*)(src + 4); \
  q2_##S = *(const f32x4*)(src + 8);  q3_##S = *(const f32x4*)(src + 12); \
  q4_##S = *(const f32x4*)(src + 16); q5_##S = *(const f32x4*)(src + 20); \
  q6_##S = *(const f32x4*)(src + 24); q7_##S = *(const f32x4*)(src + 28); }

#define H_WRITE(S, ch) { \
  char* dst = lbuf[(ch) & 1] + (hrow << 9); \
  *(s16x8*)(dst + ((hcb + 0)  ^ hswz)) = pack8(q0_##S, q1_##S); \
  *(s16x8*)(dst + ((hcb + 16) ^ hswz)) = pack8(q2_##S, q3_##S); \
  *(s16x8*)(dst + ((hcb + 32) ^ hswz)) = pack8(q4_##S, q5_##S); \
  *(s16x8*)(dst + ((hcb + 48) ^ hswz)) = pack8(q6_##S, q7_##S); }

#define H_SYNC { \
  asm volatile("s_waitcnt lgkmcnt(0)" ::: "memory"); \
  __builtin_amdgcn_s_barrier(); \
  asm volatile("" ::: "memory"); }

#define H_MFMA(ch) { \
  const char* bb = lbuf[(ch) & 1]; \
  s16x8 bv0 = *(const s16x8*)(bb + ((0 * 16 + lrow) << 9) + kboff); \
  s16x8 bv1 = *(const s16x8*)(bb + ((1 * 16 + lrow) << 9) + kboff); \
  s16x8 bv2 = *(const s16x8*)(bb + ((2 * 16 + lrow) << 9) + kboff); \
  s16x8 bv3 = *(const s16x8*)(bb + ((3 * 16 + lrow) << 9) + kboff); \
  s16x8 av0 = *(const s16x8*)(ap0 + (ch) * 256); \
  s16x8 av1 = *(const s16x8*)(ap1 + (ch) * 256); \
  __builtin_amdgcn_s_setprio(1); \
  acc[0][0] = __builtin_amdgcn_mfma_f32_16x16x32_bf16(av0, bv0, acc[0][0], 0, 0, 0); \
  acc[0][1] = __builtin_amdgcn_mfma_f32_16x16x32_bf16(av0, bv1, acc[0][1], 0, 0, 0); \
  acc[0][2] = __builtin_amdgcn_mfma_f32_16x16x32_bf16(av0, bv2, acc[0][2], 0, 0, 0); \
  acc[0][3] = __builtin_amdgcn_mfma_f32_16x16x32_bf16(av0, bv3, acc[0][3], 0, 0, 0); \
  acc[1][0] = __builtin_amdgcn_mfma_f32_16x16x32_bf16(av1, bv0, acc[1][0], 0, 0, 0); \
  acc[1][1] = __builtin_amdgcn_mfma_f32_16x16x32_bf16(av1, bv1, acc[1][1], 0, 0, 0); \
  acc[1][2] = __builtin_amdgcn_mfma_f32_16x16x32_bf16(av1, bv2, acc[1][2], 0, 0, 0); \
  acc[1][3] = __builtin_amdgcn_mfma_f32_16x16x32_bf16(av1, bv3, acc[1][3], 0, 0, 0); \
  __builtin_amdgcn_s_setprio(0); }

__global__ __launch_bounds__(512) void k_head(
    const int* __restrict__ cells, const u16* __restrict__ y2b,
    const float* __restrict__ L0, const float* __restrict__ O0,
    const float* __restrict__ L1, float* __restrict__ out) {
  __shared__ int slist[544];
  __shared__ int scnt;
  __shared__ float red[8][2048];      // 64 KB
  __shared__ char lbuf[2][32768];     // 64 KB
  const int tid = threadIdx.x;
  const int c = blockIdx.x >> 3, rt = blockIdx.x & 7;
  if (tid == 0) scnt = 0;
  __syncthreads();
  for (int i = tid; i < BATCH; i += 512)
    if (cells[i] == c) slist[atomicAdd(&scnt, 1)] = i;
  __syncthreads();
  const int ns = scnt;
  if (ns == 0) return;
  const int npad = (ns + 31) & ~31;
  for (int i = ns + tid; i < npad; i += 512) slist[i] = slist[0];
  __syncthreads();

  const int w = tid >> 6, l = tid & 63;
  const int lrow = l & 15;
  const int r0 = rt * 64;
  const float* L0c = L0 + ((size_t)c * N2 + r0) * N1;
  const int hrow = tid >> 3;
  const int hcb = (tid & 7) * 64;
  const int hswz = (hrow & 7) << 4;
  const float* hsrc = L0c + (size_t)hrow * N1 + (tid & 7) * 32;
  const int kboff = ((w * 64 + ((l >> 4) << 4)) ^ ((lrow & 7) << 4));

  f32x4 q0_A, q1_A, q2_A, q3_A, q4_A, q5_A, q6_A, q7_A;
  f32x4 q0_B, q1_B, q2_B, q3_B, q4_B, q5_B, q6_B, q7_B;

  for (int cb = 0; cb < npad; cb += 32) {
    const u16* ap0 = y2b + (size_t)slist[cb + lrow] * N1 + w * 32 + ((l >> 4) << 3);
    const u16* ap1 = y2b + (size_t)slist[cb + 16 + lrow] * N1 + w * 32 + ((l >> 4) << 3);
    f32x4 acc[2][4] = {};
    H_ISSUE(A, 0)
    H_WRITE(A, 0)
    H_ISSUE(B, 1)
    H_SYNC
    H_MFMA(0)
    H_WRITE(B, 1)
    H_ISSUE(A, 2)
    H_SYNC
    H_MFMA(1)
    H_WRITE(A, 2)
    H_ISSUE(B, 3)
    H_SYNC
    H_MFMA(2)
    H_WRITE(B, 3)
    H_SYNC
    H_MFMA(3)

    __syncthreads();
#pragma unroll
    for (int h = 0; h < 2; ++h)
#pragma unroll
      for (int fb = 0; fb < 4; ++fb)
#pragma unroll
        for (int r = 0; r < 4; ++r) {
          const int s0 = h * 16 + (l >> 4) * 4 + r;
          red[w][s0 * 64 + fb * 16 + lrow] = acc[h][fb][r];
        }
    __syncthreads();
    {
      const int s = tid >> 4;
      const int rq = (tid & 15) * 4;
      if (cb + s < ns) {
        float p = 0.f;
#pragma unroll
        for (int j = 0; j < 4; ++j) {
          const int r = rq + j, e = s * 64 + r;
          float v = red[0][e] + red[1][e] + red[2][e] + red[3][e] +
                    red[4][e] + red[5][e] + red[6][e] + red[7][e] +
                    O0[(size_t)c * N2 + r0 + r];
          v = v > 0.f ? v : 0.f;
          p += v * L1[(size_t)c * N2 + r0 + r];
        }
#pragma unroll
        for (int off = 8; off; off >>= 1) p += __shfl_xor(p, off, 16);
        if ((tid & 15) == 0) atomicAdd(&out[slist[cb + s]], p);
      }
    }
  }
}

// ---------------- launch ----------------
extern "C" void kernel_launch(void* const* d_in, const int* in_sizes, int n_in,
                              void* d_out, int out_size, void* d_ws, size_t ws_size,
                              hipStream_t stream) {
  const int*   pairs  = (const int*)d_in[0];
  const int*   cells  = (const int*)d_in[1];
  const float* attrs  = (const float*)d_in[2];
  const float* h_drug = (const float*)d_in[3];
  const float* W0     = (const float*)d_in[4];
  const float* b0     = (const float*)d_in[5];
  const float* W1     = (const float*)d_in[6];
  const float* b1     = (const float*)d_in[7];
  const float* L0     = (const float*)d_in[8];
  const float* O0     = (const float*)d_in[9];
  const float* L1     = (const float*)d_in[10];
  const float* O1     = (const float*)d_in[11];
  float* out = (float*)d_out;

  char* ws = (char*)d_ws;
  u16* xb  = (u16*)(ws);                  // 2 MB  512x2048 bf16
  u16* w0b = (u16*)(ws + (2u  << 20));    // 8 MB  2048x2048 bf16
  u16* w1b = (u16*)(ws + (10u << 20));    // 4 MB  1024x2048 bf16
  u16* y1b = (u16*)(ws + (14u << 20));    // 2 MB  512x2048 bf16
  u16* y2b = (u16*)(ws + (16u << 20));    // 1 MB  512x1024 bf16

  k_prep<<<1536, 256, 0, stream>>>(pairs, attrs, h_drug, W0, cells, O1,
                                   xb, w0b, out);
  k_gemm1<<<768, 512, 0, stream>>>(xb, w0b, b0, y1b, W1, w1b);
  k_gemm2<<<512, 256, 0, stream>>>(y1b, w1b, b1, y2b);
  k_head<<<256, 512, 0, stream>>>(cells, y2b, L0, O0, L1, out);
}

// Round 12
// 44.992 us; speedup vs baseline: 1.2207x; 1.0273x over previous
//
#include <hip/hip_runtime.h>

typedef short s16x8 __attribute__((ext_vector_type(8)));
typedef float f32x4 __attribute__((ext_vector_type(4)));
typedef unsigned short u16;

#define BATCH 512
#define HD    1023
#define K0    2048
#define N0    2048
#define N1    1024
#define N2    512

// round-to-nearest-even f32 -> bf16 (scalar path)
__device__ __forceinline__ u16 f2bf(float f) {
  unsigned u = __builtin_bit_cast(unsigned, f);
  unsigned r = (u + 0x7fffu + ((u >> 16) & 1u)) >> 16;
  return (u16)r;
}

// packed RNE convert: 8 f32 -> 8 bf16 in 4 VALU ops
__device__ __forceinline__ s16x8 pack8(f32x4 a, f32x4 b) {
  union { unsigned u[4]; s16x8 v; } r;
  asm("v_cvt_pk_bf16_f32 %0, %1, %2" : "=v"(r.u[0]) : "v"(a[0]), "v"(a[1]));
  asm("v_cvt_pk_bf16_f32 %0, %1, %2" : "=v"(r.u[1]) : "v"(a[2]), "v"(a[3]));
  asm("v_cvt_pk_bf16_f32 %0, %1, %2" : "=v"(r.u[2]) : "v"(b[0]), "v"(b[1]));
  asm("v_cvt_pk_bf16_f32 %0, %1, %2" : "=v"(r.u[3]) : "v"(b[2]), "v"(b[3]));
  return r.v;
}

// 16B load from 4B-aligned source
__device__ __forceinline__ f32x4 ld4u(const float* p) {
  f32x4 v; __builtin_memcpy(&v, p, 16); return v;
}

// ================= K0: prep — gather x (vectorized), convert W0, init out ========
__global__ __launch_bounds__(256) void k_prep(
    const int* __restrict__ pairs, const float* __restrict__ attrs,
    const float* __restrict__ h_drug, const float* __restrict__ W0,
    const int* __restrict__ cells, const float* __restrict__ O1,
    u16* __restrict__ xb, u16* __restrict__ w0b, float* __restrict__ out) {
  const int bid = blockIdx.x, tid = threadIdx.x;
  if (bid < 512) {
    const int b = bid;
    const int half = tid >> 7, ch = tid & 127;     // 2 halves x 128 chunks of 8
    const float* h = h_drug + (size_t)pairs[2 * b + half] * HD;
    u16* xr = xb + (size_t)b * K0 + half * 1024;
    f32x4 v0, v1;
    if (ch < 127) {
      v0 = ld4u(h + ch * 8);
      v1 = ld4u(h + ch * 8 + 4);
    } else {  // elems 1016..1022 + attr scalar
      v0 = ld4u(h + 1016);
      v1[0] = h[1020]; v1[1] = h[1021]; v1[2] = h[1022];
      v1[3] = attrs[4 * b + 1 + 2 * half];
    }
    *(s16x8*)(xr + ch * 8) = pack8(v0, v1);
    if (tid == 0) out[b] = O1[cells[b]];
  } else {
    const size_t e = ((size_t)(bid - 512) * 256 + tid) * 16;
    f32x4 a = *(const f32x4*)(W0 + e),     b2 = *(const f32x4*)(W0 + e + 4);
    f32x4 c = *(const f32x4*)(W0 + e + 8), d  = *(const f32x4*)(W0 + e + 12);
    *(s16x8*)(w0b + e)     = pack8(a, b2);
    *(s16x8*)(w0b + e + 8) = pack8(c, d);
  }
}

// ================= K1: gemm1 — 64x64 tile, BK=128, 8 waves, grid 256 + W1 riders ==
// y1 = relu(X * W0^T + b0), all bf16 operands. NT=16, 4-deep reg prefetch,
// 256B-row LDS with XOR swizzle byte^=(row&15)<<4, raw s_barrier+lgkmcnt(0) (T4), T5.
#define GI1(s, t) { \
  pa0_##s = *(const s16x8*)(agp0 + (size_t)(t) * 256); \
  pa1_##s = *(const s16x8*)(agp1 + (size_t)(t) * 256); \
  pb0_##s = *(const s16x8*)(bgp0 + (size_t)(t) * 256); \
  pb1_##s = *(const s16x8*)(bgp1 + (size_t)(t) * 256); }

#define GS1(s, t, DOLOAD) { \
  char* buf = lds[(s) & 1]; \
  *(s16x8*)(buf + awo0) = pa0_##s; \
  *(s16x8*)(buf + awo1) = pa1_##s; \
  *(s16x8*)(buf + 16384 + awo0) = pb0_##s; \
  *(s16x8*)(buf + 16384 + awo1) = pb1_##s; \
  asm volatile("s_waitcnt lgkmcnt(0)" ::: "memory"); \
  __builtin_amdgcn_s_barrier(); \
  asm volatile("" ::: "memory"); \
  if (DOLOAD) GI1(s, (t) + 4) \
  __builtin_amdgcn_s_setprio(1); \
  _Pragma("unroll") \
  for (int ks = 0; ks < 4; ++ks) { \
    const int kq = ((ks << 6) | lk) ^ swz; \
    s16x8 a0 = *(const s16x8*)(buf + aoff + kq); \
    s16x8 a1 = *(const s16x8*)(buf + aoff + 4096 + kq); \
    s16x8 b0 = *(const s16x8*)(buf + 16384 + boff + kq); \
    acc0 = __builtin_amdgcn_mfma_f32_16x16x32_bf16(a0, b0, acc0, 0, 0, 0); \
    acc1 = __builtin_amdgcn_mfma_f32_16x16x32_bf16(a1, b0, acc1, 0, 0, 0); \
  } \
  __builtin_amdgcn_s_setprio(0); }

__global__ __launch_bounds__(512) void k_gemm1(
    const u16* __restrict__ A, const u16* __restrict__ B,
    const float* __restrict__ bias, u16* __restrict__ Y,
    const float* __restrict__ W1f, u16* __restrict__ w1b) {
  constexpr int K = 2048, N = 2048;
  if (blockIdx.x >= 256) {  // W1 conversion riders
    const size_t e = (((size_t)blockIdx.x - 256) * 512 + threadIdx.x) * 8;
    f32x4 a = *(const f32x4*)(W1f + e), b2 = *(const f32x4*)(W1f + e + 4);
    *(s16x8*)(w1b + e) = pack8(a, b2);
    return;
  }
  __shared__ char lds[2][32768];  // A 16KB + B 16KB per buffer
  const int tid = threadIdx.x;
  const int w = tid >> 6, l = tid & 63;
  const int wr = w >> 2, wn = w & 3;
  const int lrow = l & 15;
  const int lk = (l >> 4) << 4;
  const int swz = lrow << 4;

  // XCD swizzle (256 GEMM blocks): each XCD owns 32 contiguous wgids (4 bn x 8 bm)
  const int wgid = (blockIdx.x & 7) * 32 + (blockIdx.x >> 3);
  const int bn = wgid >> 3, bm = wgid & 7;

  const size_t K2 = (size_t)K * 2;  // 4096 B/row
  const char* Ag = (const char*)A + (size_t)bm * 64 * K2;
  const char* Bg = (const char*)B + (size_t)bn * 64 * K2;

  // staging: tile 64 rows x 256B; thread covers bytes tid*16 and tid*16+8192
  const int o0 = tid * 16;
  const int ar0 = o0 >> 8, ac0 = o0 & 255;
  const char* agp0 = Ag + (size_t)ar0 * K2 + ac0;
  const char* bgp0 = Bg + (size_t)ar0 * K2 + ac0;
  const int awo0 = (ar0 << 8) + (ac0 ^ ((ar0 & 15) << 4));
  const int o1 = o0 + 8192;
  const int ar1 = o1 >> 8, ac1 = o1 & 255;
  const char* agp1 = Ag + (size_t)ar1 * K2 + ac1;
  const char* bgp1 = Bg + (size_t)ar1 * K2 + ac1;
  const int awo1 = (ar1 << 8) + (ac1 ^ ((ar1 & 15) << 4));

  const int aoff = (wr * 32 + lrow) * 256;
  const int boff = (wn * 16 + lrow) * 256;

  f32x4 acc0 = {}, acc1 = {};
  s16x8 pa0_0, pa0_1, pa0_2, pa0_3;
  s16x8 pa1_0, pa1_1, pa1_2, pa1_3;
  s16x8 pb0_0, pb0_1, pb0_2, pb0_3;
  s16x8 pb1_0, pb1_1, pb1_2, pb1_3;

  GI1(0, 0) GI1(1, 1) GI1(2, 2) GI1(3, 3)
  constexpr int NT = 16;  // K/128
  int t = 0;
  for (; t < NT - 4; t += 4) {
    GS1(0, t, 1) GS1(1, t + 1, 1) GS1(2, t + 2, 1) GS1(3, t + 3, 1)
  }
  GS1(0, t, 0) GS1(1, t + 1, 0) GS1(2, t + 2, 0) GS1(3, t + 3, 0)

  // epilogue: C/D map col=lane&15, row=(lane>>4)*4+reg
  const int colg = bn * 64 + wn * 16 + lrow;
  const int rowb = bm * 64 + wr * 32 + ((l >> 4) << 2);
  const float bv = bias[colg];
#pragma unroll
  for (int fa = 0; fa < 2; ++fa)
#pragma unroll
    for (int r = 0; r < 4; ++r) {
      float v = (fa ? acc1 : acc0)[r] + bv;
      v = v > 0.f ? v : 0.f;
      Y[(size_t)(rowb + fa * 16 + r) * N + colg] = f2bf(v);
    }
}

// ================= K2: gemm2 — 32x64 tile, BK=128, 8 waves, grid 256 ============
#define GI2(s, t) { \
  pa_##s = *(const s16x8*)(agp0 + (size_t)(t) * 256); \
  pb0_##s = *(const s16x8*)(bgp0 + (size_t)(t) * 256); \
  pb1_##s = *(const s16x8*)(bgp1 + (size_t)(t) * 256); }

#define GS2(s, t, DOLOAD) { \
  char* buf = lds[(s) & 1]; \
  *(s16x8*)(buf + awo0) = pa_##s; \
  *(s16x8*)(buf + 8192 + bwo0) = pb0_##s; \
  *(s16x8*)(buf + 8192 + bwo1) = pb1_##s; \
  asm volatile("s_waitcnt lgkmcnt(0)" ::: "memory"); \
  __builtin_amdgcn_s_barrier(); \
  asm volatile("" ::: "memory"); \
  if (DOLOAD) GI2(s, (t) + 4) \
  __builtin_amdgcn_s_setprio(1); \
  _Pragma("unroll") \
  for (int ks = 0; ks < 4; ++ks) { \
    const int kq = ((ks << 6) | lk) ^ swz; \
    s16x8 a0 = *(const s16x8*)(buf + aoff + kq); \
    s16x8 b0 = *(const s16x8*)(buf + 8192 + boff + kq); \
    acc0 = __builtin_amdgcn_mfma_f32_16x16x32_bf16(a0, b0, acc0, 0, 0, 0); \
  } \
  __builtin_amdgcn_s_setprio(0); }

__global__ __launch_bounds__(512) void k_gemm2(
    const u16* __restrict__ A, const u16* __restrict__ B,
    const float* __restrict__ bias, u16* __restrict__ Y) {
  constexpr int K = 2048, N = 1024;
  __shared__ char lds[2][24576];  // A 8KB + B 16KB per buffer
  const int tid = threadIdx.x;
  const int w = tid >> 6, l = tid & 63;
  const int wr = w >> 2, wn = w & 3;
  const int lrow = l & 15;
  const int lk = (l >> 4) << 4;
  const int swz = lrow << 4;

  // XCD swizzle (grid 256): each XCD owns 32 contiguous wgids (2 bn x 16 bm)
  const int wgid = (blockIdx.x & 7) * 32 + (blockIdx.x >> 3);
  const int bn = wgid >> 4, bm = wgid & 15;

  const size_t K2 = (size_t)K * 2;
  const char* Ag = (const char*)A + (size_t)bm * 32 * K2;
  const char* Bg = (const char*)B + (size_t)bn * 64 * K2;

  // A staging: 32 rows x 256B = 8KB; thread covers byte tid*16
  const int o0 = tid * 16;
  const int ar0 = o0 >> 8, ac0 = o0 & 255;
  const char* agp0 = Ag + (size_t)ar0 * K2 + ac0;
  const int awo0 = (ar0 << 8) + (ac0 ^ ((ar0 & 15) << 4));
  // B staging: 64 rows x 256B = 16KB; thread covers bytes tid*16 and +8192
  const char* bgp0 = Bg + (size_t)ar0 * K2 + ac0;
  const int bwo0 = awo0;
  const int o1 = o0 + 8192;
  const int br1 = o1 >> 8, bc1 = o1 & 255;
  const char* bgp1 = Bg + (size_t)br1 * K2 + bc1;
  const int bwo1 = (br1 << 8) + (bc1 ^ ((br1 & 15) << 4));

  const int aoff = (wr * 16 + lrow) * 256;
  const int boff = (wn * 16 + lrow) * 256;

  f32x4 acc0 = {};
  s16x8 pa_0, pa_1, pa_2, pa_3;
  s16x8 pb0_0, pb0_1, pb0_2, pb0_3;
  s16x8 pb1_0, pb1_1, pb1_2, pb1_3;

  GI2(0, 0) GI2(1, 1) GI2(2, 2) GI2(3, 3)
  constexpr int NT = 16;
  int t = 0;
  for (; t < NT - 4; t += 4) {
    GS2(0, t, 1) GS2(1, t + 1, 1) GS2(2, t + 2, 1) GS2(3, t + 3, 1)
  }
  GS2(0, t, 0) GS2(1, t + 1, 0) GS2(2, t + 2, 0) GS2(3, t + 3, 0)

  const int colg = bn * 64 + wn * 16 + lrow;
  const int rowb = bm * 32 + wr * 16 + ((l >> 4) << 2);
  const float bv = bias[colg];
#pragma unroll
  for (int r = 0; r < 4; ++r) {
    float v = acc0[r] + bv;
    v = v > 0.f ? v : 0.f;
    Y[(size_t)(rowb + r) * N + colg] = f2bf(v);
  }
}

// ================= K3: head; atomicAdd partials into out =============
#define H_ISSUE(S, ch) { \
  const float* src = hsrc + (ch) * 256; \
  q0_##S = *(const f32x4*)(src);      q1_##S = *(const f32x4*)(src + 4); \
  q2_##S = *(const f32x4*)(src + 8);  q3_##S = *(const f32x4*)(src + 12); \
  q4_##S = *(const f32x4*)(src + 16); q5_##S = *(const f32x4*)(src + 20); \
  q6_##S = *(const f32x4*)(src + 24); q7_##S = *(const f32x4*)(src + 28); }

#define H_WRITE(S, ch) { \
  char* dst = lbuf[(ch) & 1] + (hrow << 9); \
  *(s16x8*)(dst + ((hcb + 0)  ^ hswz)) = pack8(q0_##S, q1_##S); \
  *(s16x8*)(dst + ((hcb + 16) ^ hswz)) = pack8(q2_##S, q3_##S); \
  *(s16x8*)(dst + ((hcb + 32) ^ hswz)) = pack8(q4_##S, q5_##S); \
  *(s16x8*)(dst + ((hcb + 48) ^ hswz)) = pack8(q6_##S, q7_##S); }

#define H_SYNC { \
  asm volatile("s_waitcnt lgkmcnt(0)" ::: "memory"); \
  __builtin_amdgcn_s_barrier(); \
  asm volatile("" ::: "memory"); }

#define H_MFMA(ch) { \
  const char* bb = lbuf[(ch) & 1]; \
  s16x8 bv0 = *(const s16x8*)(bb + ((0 * 16 + lrow) << 9) + kboff); \
  s16x8 bv1 = *(const s16x8*)(bb + ((1 * 16 + lrow) << 9) + kboff); \
  s16x8 bv2 = *(const s16x8*)(bb + ((2 * 16 + lrow) << 9) + kboff); \
  s16x8 bv3 = *(const s16x8*)(bb + ((3 * 16 + lrow) << 9) + kboff); \
  s16x8 av0 = *(const s16x8*)(ap0 + (ch) * 256); \
  s16x8 av1 = *(const s16x8*)(ap1 + (ch) * 256); \
  __builtin_amdgcn_s_setprio(1); \
  acc[0][0] = __builtin_amdgcn_mfma_f32_16x16x32_bf16(av0, bv0, acc[0][0], 0, 0, 0); \
  acc[0][1] = __builtin_amdgcn_mfma_f32_16x16x32_bf16(av0, bv1, acc[0][1], 0, 0, 0); \
  acc[0][2] = __builtin_amdgcn_mfma_f32_16x16x32_bf16(av0, bv2, acc[0][2], 0, 0, 0); \
  acc[0][3] = __builtin_amdgcn_mfma_f32_16x16x32_bf16(av0, bv3, acc[0][3], 0, 0, 0); \
  acc[1][0] = __builtin_amdgcn_mfma_f32_16x16x32_bf16(av1, bv0, acc[1][0], 0, 0, 0); \
  acc[1][1] = __builtin_amdgcn_mfma_f32_16x16x32_bf16(av1, bv1, acc[1][1], 0, 0, 0); \
  acc[1][2] = __builtin_amdgcn_mfma_f32_16x16x32_bf16(av1, bv2, acc[1][2], 0, 0, 0); \
  acc[1][3] = __builtin_amdgcn_mfma_f32_16x16x32_bf16(av1, bv3, acc[1][3], 0, 0, 0); \
  __builtin_amdgcn_s_setprio(0); }

__global__ __launch_bounds__(512) void k_head(
    const int* __restrict__ cells, const u16* __restrict__ y2b,
    const float* __restrict__ L0, const float* __restrict__ O0,
    const float* __restrict__ L1, float* __restrict__ out) {
  __shared__ int slist[544];
  __shared__ int scnt;
  __shared__ float red[8][2048];      // 64 KB
  __shared__ char lbuf[2][32768];     // 64 KB
  const int tid = threadIdx.x;
  const int c = blockIdx.x >> 3, rt = blockIdx.x & 7;
  if (tid == 0) scnt = 0;
  __syncthreads();
  for (int i = tid; i < BATCH; i += 512)
    if (cells[i] == c) slist[atomicAdd(&scnt, 1)] = i;
  __syncthreads();
  const int ns = scnt;
  if (ns == 0) return;
  const int npad = (ns + 31) & ~31;
  for (int i = ns + tid; i < npad; i += 512) slist[i] = slist[0];
  __syncthreads();

  const int w = tid >> 6, l = tid & 63;
  const int lrow = l & 15;
  const int r0 = rt * 64;
  const float* L0c = L0 + ((size_t)c * N2 + r0) * N1;
  const int hrow = tid >> 3;
  const int hcb = (tid & 7) * 64;
  const int hswz = (hrow & 7) << 4;
  const float* hsrc = L0c + (size_t)hrow * N1 + (tid & 7) * 32;
  const int kboff = ((w * 64 + ((l >> 4) << 4)) ^ ((lrow & 7) << 4));

  f32x4 q0_A, q1_A, q2_A, q3_A, q4_A, q5_A, q6_A, q7_A;
  f32x4 q0_B, q1_B, q2_B, q3_B, q4_B, q5_B, q6_B, q7_B;

  for (int cb = 0; cb < npad; cb += 32) {
    const u16* ap0 = y2b + (size_t)slist[cb + lrow] * N1 + w * 32 + ((l >> 4) << 3);
    const u16* ap1 = y2b + (size_t)slist[cb + 16 + lrow] * N1 + w * 32 + ((l >> 4) << 3);
    f32x4 acc[2][4] = {};
    H_ISSUE(A, 0)
    H_WRITE(A, 0)
    H_ISSUE(B, 1)
    H_SYNC
    H_MFMA(0)
    H_WRITE(B, 1)
    H_ISSUE(A, 2)
    H_SYNC
    H_MFMA(1)
    H_WRITE(A, 2)
    H_ISSUE(B, 3)
    H_SYNC
    H_MFMA(2)
    H_WRITE(B, 3)
    H_SYNC
    H_MFMA(3)

    __syncthreads();
#pragma unroll
    for (int h = 0; h < 2; ++h)
#pragma unroll
      for (int fb = 0; fb < 4; ++fb)
#pragma unroll
        for (int r = 0; r < 4; ++r) {
          const int s0 = h * 16 + (l >> 4) * 4 + r;
          red[w][s0 * 64 + fb * 16 + lrow] = acc[h][fb][r];
        }
    __syncthreads();
    {
      const int s = tid >> 4;
      const int rq = (tid & 15) * 4;
      if (cb + s < ns) {
        float p = 0.f;
#pragma unroll
        for (int j = 0; j < 4; ++j) {
          const int r = rq + j, e = s * 64 + r;
          float v = red[0][e] + red[1][e] + red[2][e] + red[3][e] +
                    red[4][e] + red[5][e] + red[6][e] + red[7][e] +
                    O0[(size_t)c * N2 + r0 + r];
          v = v > 0.f ? v : 0.f;
          p += v * L1[(size_t)c * N2 + r0 + r];
        }
#pragma unroll
        for (int off = 8; off; off >>= 1) p += __shfl_xor(p, off, 16);
        if ((tid & 15) == 0) atomicAdd(&out[slist[cb + s]], p);
      }
    }
  }
}

// ---------------- launch ----------------
extern "C" void kernel_launch(void* const* d_in, const int* in_sizes, int n_in,
                              void* d_out, int out_size, void* d_ws, size_t ws_size,
                              hipStream_t stream) {
  const int*   pairs  = (const int*)d_in[0];
  const int*   cells  = (const int*)d_in[1];
  const float* attrs  = (const float*)d_in[2];
  const float* h_drug = (const float*)d_in[3];
  const float* W0     = (const float*)d_in[4];
  const float* b0     = (const float*)d_in[5];
  const float* W1     = (const float*)d_in[6];
  const float* b1     = (const float*)d_in[7];
  const float* L0     = (const float*)d_in[8];
  const float* O0     = (const float*)d_in[9];
  const float* L1     = (const float*)d_in[10];
  const float* O1     = (const float*)d_in[11];
  float* out = (float*)d_out;

  char* ws = (char*)d_ws;
  u16* xb  = (u16*)(ws);                  // 2 MB  512x2048 bf16
  u16* w0b = (u16*)(ws + (2u  << 20));    // 8 MB  2048x2048 bf16
  u16* w1b = (u16*)(ws + (10u << 20));    // 4 MB  1024x2048 bf16
  u16* y1b = (u16*)(ws + (14u << 20));    // 2 MB  512x2048 bf16
  u16* y2b = (u16*)(ws + (16u << 20));    // 1 MB  512x1024 bf16

  k_prep<<<1536, 256, 0, stream>>>(pairs, attrs, h_drug, W0, cells, O1,
                                   xb, w0b, out);
  k_gemm1<<<768, 512, 0, stream>>>(xb, w0b, b0, y1b, W1, w1b);
  k_gemm2<<<256, 512, 0, stream>>>(y1b, w1b, b1, y2b);
  k_head<<<256, 512, 0, stream>>>(cells, y2b, L0, O0, L1, out);
}